// Round 4
// baseline (363.361 us; speedup 1.0000x reference)
//
#include <hip/hip_runtime.h>
#include <stdint.h>

// Problem geometry
constexpr int B = 2, X = 256, Y = 256, Z = 64;
constexpr int CO = X * Y * Z;                       // channel stride (elements)
constexpr int YZ = Y * Z;
constexpr long long N_PTS   = (long long)B * X * Y * Z;              // 8388608
constexpr long long M_CELLS = (long long)B * (X-1) * (Y-1) * (Z-1);  // 8193150

constexpr int RPB = 16;                 // y-rows per block
constexpr int TPB = 256;                // 4 waves
constexpr int WPB = TPB / 64;
constexpr int BLOCKS = B * (Y / RPB) * X;   // 8192 one-shot blocks

#define EPSc 1e-10f
#define SIXTH (1.0f / 6.0f)
#define RCPF(v) __builtin_amdgcn_rcpf(v)

typedef float fvec4 __attribute__((ext_vector_type(4)));

#define F4C(v, c) (((c) == 0) ? (v).x : ((c) == 1) ? (v).y : ((c) == 2) ? (v).z : (v).w)
#define LD4(base, off) (*(const fvec4*)((base) + (off)))

// 6 blocks/CU (24-wave ceiling; VGPR cap 85 leaves slack for the 19-vec4 live set)
__global__ __launch_bounds__(TPB, 6) void loss_main(const float* __restrict__ outs,
                                                    const float* __restrict__ tgts,
                                                    double* __restrict__ partial) {
    const int lane = threadIdx.x & 63;
    const int wv   = threadIdx.x >> 6;

    // XCD-aware bijective swizzle: 8192 = 8 XCDs x 1024. Consecutive LOGICAL
    // blocks (x and x+1, which share the x+1 stencil column) land on the same XCD.
    const int bid = (int)blockIdx.x;
    const int blk = (bid & 7) * (BLOCKS / 8) + (bid >> 3);

    // blk = ((b*16 + sy)*256 + x) : x fastest
    const int b  = blk >> 12;
    const int r  = blk & 4095;
    const int sy = r >> 8;
    const int x  = r & 255;

    const int row_l = wv * 4 + (lane >> 4);   // 0..15 (block-local y row)
    const int zi    = (lane & 15) << 2;       // 0,4,...,60
    const int y     = sy * RPB + row_l;

    const int xp = (x < X - 1) ? (x + 1) : x;     // clamped (cells masked at x=255)
    const int yp = (y < Y - 1) ? (y + 1) : y;     // clamped (cells masked at y=255)
    const bool xvalid = (x < X - 1);              // block-uniform
    const bool yvalid = (y < Y - 1);

    const float* ob = outs + (size_t)b * 3 * CO;
    const float* tb = tgts + (size_t)b * 4 * CO;

    // 32-bit element offsets (max ~4.2M elems, 16.8MB bytes: saddr-form loads,
    // address calc stays in 32-bit VALU)
    const uint32_t o00 = (uint32_t)x  * YZ + (uint32_t)y  * Z + zi;
    const uint32_t o01 = (uint32_t)x  * YZ + (uint32_t)yp * Z + zi;
    const uint32_t o10 = (uint32_t)xp * YZ + (uint32_t)y  * Z + zi;
    const uint32_t o11 = (uint32_t)xp * YZ + (uint32_t)yp * Z + zi;
    constexpr uint32_t C1 = (uint32_t)CO, C2 = 2u * CO, C3 = 3u * CO;

    // ---- issue ALL loads up front (independent; TLP + ILP hide latency) ----
    // No nontemporal hints: all 235 MB of inputs fit the 256 MB L3; NT was
    // forcing the 100 MB of pointwise targets to HBM (round-3 FETCH evidence).
    const fvec4 bx00v = LD4(ob, o00);
    const fvec4 by00v = LD4(ob, C1 + o00);
    const fvec4 bz00v = LD4(ob, C2 + o00);
    const fvec4 zc00v = LD4(tb, C3 + o00);
    const fvec4 bx01v = LD4(ob, o01);
    const fvec4 by01v = LD4(ob, C1 + o01);
    const fvec4 bz01v = LD4(ob, C2 + o01);
    const fvec4 zc01v = LD4(tb, C3 + o01);
    const fvec4 bx10v = LD4(ob, o10);
    const fvec4 by10v = LD4(ob, C1 + o10);
    const fvec4 bz10v = LD4(ob, C2 + o10);
    const fvec4 zc10v = LD4(tb, C3 + o10);
    const fvec4 bx11v = LD4(ob, o11);
    const fvec4 by11v = LD4(ob, C1 + o11);
    const fvec4 bz11v = LD4(ob, C2 + o11);
    const fvec4 zc11v = LD4(tb, C3 + o11);
    const fvec4 t0 = LD4(tb, o00);
    const fvec4 t1 = LD4(tb, C1 + o00);
    const fvec4 t2 = LD4(tb, C2 + o00);

    double s_pt, s_dv = 0.0;

    // ---- pointwise losses at own point ----
    {
        float pt4 = 0.0f;
        #pragma unroll
        for (int c = 0; c < 4; ++c) {
            const float bxp = F4C(bx00v, c), byp = F4C(by00v, c), bzp = F4C(bz00v, c);
            const float bxt = F4C(t0, c), byt = F4C(t1, c), bzt = F4C(t2, c);
            const float bxt2 = bxt * bxt, byt2 = byt * byt, bzt2 = bzt * bzt;
            const float dxy = bxt2 + byt2;
            const float tq = bxp * bxp + byp * byp - dxy;
            const float e1 = tq * tq * RCPF(dxy + EPSc);
            const float dd = bzp - bzt;
            const float dd2 = dd * dd;
            const float e2 = dd2 * dd2 * RCPF(bzt2 + EPSc);
            const float cr = bxp * byt - byp * bxt;
            const float e3 = cr * cr * RCPF(dxy + bzt2 + EPSc);
            pt4 += e1 + e2 + e3;
        }
        s_pt = (double)pt4;
    }

    // ---- divergence cells between cols x (00/01) and x+1 (10/11) ----
    if (xvalid) {                        // block-uniform
        float sxp[5], sxm[5], syp[5], sym[5];
        float zxp[5], zxm[5], zyp[5], zym[5];
        float Sx[5], Sy[5], Sz[5], G2[5];

        #pragma unroll
        for (int t = 0; t < 4; ++t) {
            const float bx00 = F4C(bx00v, t), bx10 = F4C(bx10v, t);
            const float bx01 = F4C(bx01v, t), bx11 = F4C(bx11v, t);
            const float by00 = F4C(by00v, t), by10 = F4C(by10v, t);
            const float by01 = F4C(by01v, t), by11 = F4C(by11v, t);
            const float bz00 = F4C(bz00v, t), bz10 = F4C(bz10v, t);
            const float bz01 = F4C(bz01v, t), bz11 = F4C(bz11v, t);
            const float zc00 = F4C(zc00v, t), zc10 = F4C(zc10v, t);
            const float zc01 = F4C(zc01v, t), zc11 = F4C(zc11v, t);

            sxp[t] = bx10 + bx11;   sxm[t] = bx00 + bx01;
            syp[t] = by01 + by11;   sym[t] = by00 + by10;
            zxp[t] = zc10 + zc11;   zxm[t] = zc00 + zc01;
            zyp[t] = zc01 + zc11;   zym[t] = zc00 + zc10;
            Sx[t] = sxp[t] + sxm[t];
            Sy[t] = syp[t] + sym[t];
            Sz[t] = (bz00 + bz01) + (bz10 + bz11);
            G2[t] = 0.025f * Sz[t]
                  + SIXTH * ((bx00 + sxp[t]) * (zc00 - zc10)
                           + (bx01 + sxp[t]) * (zc01 - zc11)
                           + (by10 + syp[t]) * (zc10 - zc11)
                           + (by00 + syp[t]) * (zc00 - zc01));
        }
        // level 4 = lane+1's level 0 (z is the lane-contiguous dim)
        sxp[4] = __shfl_down(sxp[0], 1);
        sxm[4] = __shfl_down(sxm[0], 1);
        syp[4] = __shfl_down(syp[0], 1);
        sym[4] = __shfl_down(sym[0], 1);
        zxp[4] = __shfl_down(zxp[0], 1);
        zxm[4] = __shfl_down(zxm[0], 1);
        zyp[4] = __shfl_down(zyp[0], 1);
        zym[4] = __shfl_down(zym[0], 1);
        Sz[4]  = __shfl_down(Sz[0],  1);
        G2[4]  = __shfl_down(G2[0],  1);
        Sx[4] = sxp[4] + sxm[4];
        Sy[4] = syp[4] + sym[4];

        float dv4 = 0.0f;
        #pragma unroll
        for (int c = 0; c < 4; ++c) {
            const float fx = (sxp[c] + sxp[c+1]) * (zxp[c+1] - zxp[c])
                           - (sxm[c] + sxm[c+1]) * (zxm[c+1] - zxm[c])
                           + (syp[c] + syp[c+1]) * (zyp[c+1] - zyp[c])
                           - (sym[c] + sym[c+1]) * (zym[c+1] - zym[c]);
            const float num2 = 0.125f * fx + (G2[c+1] - G2[c]);
            const float SxS = Sx[c] + Sx[c+1];
            const float SyS = Sy[c] + Sy[c+1];
            const float SzS = Sz[c] + Sz[c+1];
            const float q = SxS * SxS + SyS * SyS + SzS * SzS;
            const float den = 0.015625f * q + EPSc;
            const float v = num2 * num2 * RCPF(den);
            const bool ok = yvalid && ((zi + c) < Z - 1);
            dv4 += ok ? v : 0.0f;
        }
        s_dv = (double)dv4;
    }

    // wave reduction (64 lanes)
    for (int off = 32; off > 0; off >>= 1) {
        s_pt += __shfl_down(s_pt, off);
        s_dv += __shfl_down(s_dv, off);
    }

    __shared__ double lds_pt[WPB];
    __shared__ double lds_dv[WPB];
    if (lane == 0) { lds_pt[wv] = s_pt; lds_dv[wv] = s_dv; }
    __syncthreads();
    if (threadIdx.x == 0) {
        double p = 0.0, d = 0.0;
        #pragma unroll
        for (int w = 0; w < WPB; ++w) { p += lds_pt[w]; d += lds_dv[w]; }
        // write by LOGICAL block id -> partial[] contents identical to unswizzled
        partial[2 * blk]     = p;
        partial[2 * blk + 1] = d;
    }
}

__global__ __launch_bounds__(256) void loss_finalize(const double* __restrict__ partial,
                                                     float* __restrict__ out) {
    double s0 = 0.0, s1 = 0.0;
    for (int i = threadIdx.x; i < BLOCKS; i += 256) {
        s0 += partial[2 * i];
        s1 += partial[2 * i + 1];
    }
    const int lane = threadIdx.x & 63;
    const int wave = threadIdx.x >> 6;
    for (int off = 32; off > 0; off >>= 1) {
        s0 += __shfl_down(s0, off);
        s1 += __shfl_down(s1, off);
    }
    __shared__ double l0[4], l1[4];
    if (lane == 0) { l0[wave] = s0; l1[wave] = s1; }
    __syncthreads();
    if (threadIdx.x == 0) {
        double p = 0.0, d = 0.0;
        #pragma unroll
        for (int w = 0; w < 4; ++w) { p += l0[w]; d += l1[w]; }
        // out0 = W_B*loss_b + W_PARALLEL*loss_parallel = 1000 * sum_pt / N
        const double out0 = 1000.0 * (p / (double)N_PTS);
        // s_dv accumulates v = num2^2/den with num = 0.1*num2:
        //   out1 = 100 * (0.01 * sum_v / M) / 1e-4 = 1e4 * sum_v / M
        const double out1 = 10000.0 * (d / (double)M_CELLS);
        out[0] = (float)out0;
        out[1] = (float)out1;
    }
}

extern "C" void kernel_launch(void* const* d_in, const int* in_sizes, int n_in,
                              void* d_out, int out_size, void* d_ws, size_t ws_size,
                              hipStream_t stream) {
    const float* outs = (const float*)d_in[0];   // (2,3,256,256,64) f32
    const float* tgts = (const float*)d_in[1];   // (2,4,256,256,64) f32
    float* out = (float*)d_out;                  // 2 scalars f32
    double* partial = (double*)d_ws;             // BLOCKS*2 doubles = 128 KB

    loss_main<<<BLOCKS, TPB, 0, stream>>>(outs, tgts, partial);
    loss_finalize<<<1, 256, 0, stream>>>(partial, out);
}

// Round 5
// 268.550 us; speedup vs baseline: 1.3530x; 1.3530x over previous
//
#include <hip/hip_runtime.h>
#include <stdint.h>

// Problem geometry
constexpr int B = 2, X = 256, Y = 256, Z = 64;
constexpr int CO = X * Y * Z;                       // channel stride (elements)
constexpr int YZ = Y * Z;
constexpr long long N_PTS   = (long long)B * X * Y * Z;              // 8388608
constexpr long long M_CELLS = (long long)B * (X-1) * (Y-1) * (Z-1);  // 8193150

constexpr int RPB = 16;                 // y-rows per block
constexpr int TPB = 256;                // 4 waves
constexpr int WPB = TPB / 64;
constexpr int BLOCKS = B * (Y / RPB) * X;   // 8192 one-shot blocks

#define EPSc 1e-10f
#define SIXTH (1.0f / 6.0f)
#define RCPF(v) __builtin_amdgcn_rcpf(v)

typedef float fvec4 __attribute__((ext_vector_type(4)));

#define F4C(v, c) (((c) == 0) ? (v).x : ((c) == 1) ? (v).y : ((c) == 2) ? (v).z : (v).w)
#define LD4(base, off)  (*(const fvec4*)((base) + (off)))
#define LDNT(base, off) __builtin_nontemporal_load((const fvec4*)((base) + (off)))

// No min-waves clamp: let the allocator hold the full 19-vec4 load batch live
// (~96-128 VGPR). Round-4 evidence: (256,6) clamp -> VGPR 40 + 285 MB spills.
// Round-3 evidence: VGPR 60 serializes the loads -> 15.7k-cycle block lifetime.
__global__ __launch_bounds__(TPB) void loss_main(const float* __restrict__ outs,
                                                 const float* __restrict__ tgts,
                                                 double* __restrict__ partial) {
    const int lane = threadIdx.x & 63;
    const int wv   = threadIdx.x >> 6;

    // XCD-aware bijective swizzle: 8192 = 8 XCDs x 1024. Consecutive LOGICAL
    // blocks (x and x+1, which share the x+1 stencil column) land on the same XCD.
    const int bid = (int)blockIdx.x;
    const int blk = (bid & 7) * (BLOCKS / 8) + (bid >> 3);

    // blk = ((b*16 + sy)*256 + x) : x fastest
    const int b  = blk >> 12;
    const int r  = blk & 4095;
    const int sy = r >> 8;
    const int x  = r & 255;

    const int row_l = wv * 4 + (lane >> 4);   // 0..15 (block-local y row)
    const int zi    = (lane & 15) << 2;       // 0,4,...,60
    const int y     = sy * RPB + row_l;

    const int xp = (x < X - 1) ? (x + 1) : x;     // clamped (cells masked at x=255)
    const int yp = (y < Y - 1) ? (y + 1) : y;     // clamped (cells masked at y=255)
    const bool xvalid = (x < X - 1);              // block-uniform
    const bool yvalid = (y < Y - 1);

    const float* ob = outs + (size_t)b * 3 * CO;
    const float* tb = tgts + (size_t)b * 4 * CO;

    // 32-bit element offsets (saddr-form loads, 32-bit VALU address calc)
    const uint32_t o00 = (uint32_t)x  * YZ + (uint32_t)y  * Z + zi;
    const uint32_t o01 = (uint32_t)x  * YZ + (uint32_t)yp * Z + zi;
    const uint32_t o10 = (uint32_t)xp * YZ + (uint32_t)y  * Z + zi;
    const uint32_t o11 = (uint32_t)xp * YZ + (uint32_t)yp * Z + zi;
    constexpr uint32_t C1 = (uint32_t)CO, C2 = 2u * CO, C3 = 3u * CO;

    // ---- issue ALL 19 loads up front; sched_barrier forbids compute between
    //      them, so one latency covers the whole batch. Pointwise inputs are
    //      the OLDEST 6 -> compiler consumes them at vmcnt(13) while the
    //      13 stencil loads are still in flight. ----
    const fvec4 bx00v = LD4 (ob, o00);
    const fvec4 by00v = LD4 (ob, C1 + o00);
    const fvec4 bz00v = LD4 (ob, C2 + o00);
    const fvec4 t0    = LDNT(tb, o00);            // streaming, no reuse
    const fvec4 t1    = LDNT(tb, C1 + o00);
    const fvec4 t2    = LDNT(tb, C2 + o00);
    const fvec4 zc00v = LD4 (tb, C3 + o00);
    const fvec4 bx01v = LD4 (ob, o01);
    const fvec4 by01v = LD4 (ob, C1 + o01);
    const fvec4 bz01v = LD4 (ob, C2 + o01);
    const fvec4 zc01v = LD4 (tb, C3 + o01);
    const fvec4 bx10v = LD4 (ob, o10);
    const fvec4 by10v = LD4 (ob, C1 + o10);
    const fvec4 bz10v = LD4 (ob, C2 + o10);
    const fvec4 zc10v = LD4 (tb, C3 + o10);
    const fvec4 bx11v = LD4 (ob, o11);
    const fvec4 by11v = LD4 (ob, C1 + o11);
    const fvec4 bz11v = LD4 (ob, C2 + o11);
    const fvec4 zc11v = LD4 (tb, C3 + o11);
    __builtin_amdgcn_sched_barrier(0);   // pin: all loads issued before any compute

    double s_pt, s_dv = 0.0;

    // ---- pointwise losses at own point (oldest 6 loads) ----
    {
        float pt4 = 0.0f;
        #pragma unroll
        for (int c = 0; c < 4; ++c) {
            const float bxp = F4C(bx00v, c), byp = F4C(by00v, c), bzp = F4C(bz00v, c);
            const float bxt = F4C(t0, c), byt = F4C(t1, c), bzt = F4C(t2, c);
            const float bxt2 = bxt * bxt, byt2 = byt * byt, bzt2 = bzt * bzt;
            const float dxy = bxt2 + byt2;
            const float tq = bxp * bxp + byp * byp - dxy;
            const float e1 = tq * tq * RCPF(dxy + EPSc);
            const float dd = bzp - bzt;
            const float dd2 = dd * dd;
            const float e2 = dd2 * dd2 * RCPF(bzt2 + EPSc);
            const float cr = bxp * byt - byp * bxt;
            const float e3 = cr * cr * RCPF(dxy + bzt2 + EPSc);
            pt4 += e1 + e2 + e3;
        }
        s_pt = (double)pt4;
    }

    // ---- divergence cells between cols x (00/01) and x+1 (10/11) ----
    if (xvalid) {                        // block-uniform
        float sxp[5], sxm[5], syp[5], sym[5];
        float zxp[5], zxm[5], zyp[5], zym[5];
        float Sx[5], Sy[5], Sz[5], G2[5];

        #pragma unroll
        for (int t = 0; t < 4; ++t) {
            const float bx00 = F4C(bx00v, t), bx10 = F4C(bx10v, t);
            const float bx01 = F4C(bx01v, t), bx11 = F4C(bx11v, t);
            const float by00 = F4C(by00v, t), by10 = F4C(by10v, t);
            const float by01 = F4C(by01v, t), by11 = F4C(by11v, t);
            const float bz00 = F4C(bz00v, t), bz10 = F4C(bz10v, t);
            const float bz01 = F4C(bz01v, t), bz11 = F4C(bz11v, t);
            const float zc00 = F4C(zc00v, t), zc10 = F4C(zc10v, t);
            const float zc01 = F4C(zc01v, t), zc11 = F4C(zc11v, t);

            sxp[t] = bx10 + bx11;   sxm[t] = bx00 + bx01;
            syp[t] = by01 + by11;   sym[t] = by00 + by10;
            zxp[t] = zc10 + zc11;   zxm[t] = zc00 + zc01;
            zyp[t] = zc01 + zc11;   zym[t] = zc00 + zc10;
            Sx[t] = sxp[t] + sxm[t];
            Sy[t] = syp[t] + sym[t];
            Sz[t] = (bz00 + bz01) + (bz10 + bz11);
            G2[t] = 0.025f * Sz[t]
                  + SIXTH * ((bx00 + sxp[t]) * (zc00 - zc10)
                           + (bx01 + sxp[t]) * (zc01 - zc11)
                           + (by10 + syp[t]) * (zc10 - zc11)
                           + (by00 + syp[t]) * (zc00 - zc01));
        }
        // level 4 = lane+1's level 0 (z is the lane-contiguous dim)
        sxp[4] = __shfl_down(sxp[0], 1);
        sxm[4] = __shfl_down(sxm[0], 1);
        syp[4] = __shfl_down(syp[0], 1);
        sym[4] = __shfl_down(sym[0], 1);
        zxp[4] = __shfl_down(zxp[0], 1);
        zxm[4] = __shfl_down(zxm[0], 1);
        zyp[4] = __shfl_down(zyp[0], 1);
        zym[4] = __shfl_down(zym[0], 1);
        Sz[4]  = __shfl_down(Sz[0],  1);
        G2[4]  = __shfl_down(G2[0],  1);
        Sx[4] = sxp[4] + sxm[4];
        Sy[4] = syp[4] + sym[4];

        float dv4 = 0.0f;
        #pragma unroll
        for (int c = 0; c < 4; ++c) {
            const float fx = (sxp[c] + sxp[c+1]) * (zxp[c+1] - zxp[c])
                           - (sxm[c] + sxm[c+1]) * (zxm[c+1] - zxm[c])
                           + (syp[c] + syp[c+1]) * (zyp[c+1] - zyp[c])
                           - (sym[c] + sym[c+1]) * (zym[c+1] - zym[c]);
            const float num2 = 0.125f * fx + (G2[c+1] - G2[c]);
            const float SxS = Sx[c] + Sx[c+1];
            const float SyS = Sy[c] + Sy[c+1];
            const float SzS = Sz[c] + Sz[c+1];
            const float q = SxS * SxS + SyS * SyS + SzS * SzS;
            const float den = 0.015625f * q + EPSc;
            const float v = num2 * num2 * RCPF(den);
            const bool ok = yvalid && ((zi + c) < Z - 1);
            dv4 += ok ? v : 0.0f;
        }
        s_dv = (double)dv4;
    }

    // wave reduction (64 lanes)
    for (int off = 32; off > 0; off >>= 1) {
        s_pt += __shfl_down(s_pt, off);
        s_dv += __shfl_down(s_dv, off);
    }

    __shared__ double lds_pt[WPB];
    __shared__ double lds_dv[WPB];
    if (lane == 0) { lds_pt[wv] = s_pt; lds_dv[wv] = s_dv; }
    __syncthreads();
    if (threadIdx.x == 0) {
        double p = 0.0, d = 0.0;
        #pragma unroll
        for (int w = 0; w < WPB; ++w) { p += lds_pt[w]; d += lds_dv[w]; }
        // write by LOGICAL block id -> partial[] contents identical to unswizzled
        partial[2 * blk]     = p;
        partial[2 * blk + 1] = d;
    }
}

__global__ __launch_bounds__(256) void loss_finalize(const double* __restrict__ partial,
                                                     float* __restrict__ out) {
    double s0 = 0.0, s1 = 0.0;
    for (int i = threadIdx.x; i < BLOCKS; i += 256) {
        s0 += partial[2 * i];
        s1 += partial[2 * i + 1];
    }
    const int lane = threadIdx.x & 63;
    const int wave = threadIdx.x >> 6;
    for (int off = 32; off > 0; off >>= 1) {
        s0 += __shfl_down(s0, off);
        s1 += __shfl_down(s1, off);
    }
    __shared__ double l0[4], l1[4];
    if (lane == 0) { l0[wave] = s0; l1[wave] = s1; }
    __syncthreads();
    if (threadIdx.x == 0) {
        double p = 0.0, d = 0.0;
        #pragma unroll
        for (int w = 0; w < 4; ++w) { p += l0[w]; d += l1[w]; }
        // out0 = W_B*loss_b + W_PARALLEL*loss_parallel = 1000 * sum_pt / N
        const double out0 = 1000.0 * (p / (double)N_PTS);
        // s_dv accumulates v = num2^2/den with num = 0.1*num2:
        //   out1 = 100 * (0.01 * sum_v / M) / 1e-4 = 1e4 * sum_v / M
        const double out1 = 10000.0 * (d / (double)M_CELLS);
        out[0] = (float)out0;
        out[1] = (float)out1;
    }
}

extern "C" void kernel_launch(void* const* d_in, const int* in_sizes, int n_in,
                              void* d_out, int out_size, void* d_ws, size_t ws_size,
                              hipStream_t stream) {
    const float* outs = (const float*)d_in[0];   // (2,3,256,256,64) f32
    const float* tgts = (const float*)d_in[1];   // (2,4,256,256,64) f32
    float* out = (float*)d_out;                  // 2 scalars f32
    double* partial = (double*)d_ws;             // BLOCKS*2 doubles = 128 KB

    loss_main<<<BLOCKS, TPB, 0, stream>>>(outs, tgts, partial);
    loss_finalize<<<1, 256, 0, stream>>>(partial, out);
}

// Round 6
// 250.164 us; speedup vs baseline: 1.4525x; 1.0735x over previous
//
#include <hip/hip_runtime.h>
#include <stdint.h>

// Problem geometry
constexpr int B = 2, X = 256, Y = 256, Z = 64;
constexpr int CO = X * Y * Z;                       // channel stride (elements)
constexpr int YZ = Y * Z;
constexpr long long N_PTS   = (long long)B * X * Y * Z;              // 8388608
constexpr long long M_CELLS = (long long)B * (X-1) * (Y-1) * (Z-1);  // 8193150

constexpr int RPB = 16;                 // y-rows per block
constexpr int XS  = 4;                  // x-columns (pointwise) per block
constexpr int TPB = 256;                // 4 waves
constexpr int WPB = TPB / 64;
constexpr int BLOCKS = B * (Y / RPB) * (X / XS);   // 2*16*64 = 2048

#define EPSc 1e-10f
#define SIXTH (1.0f / 6.0f)
#define RCPF(v) __builtin_amdgcn_rcpf(v)

typedef float fvec4 __attribute__((ext_vector_type(4)));

#define F4C(v, c) (((c) == 0) ? (v).x : ((c) == 1) ? (v).y : ((c) == 2) ? (v).z : (v).w)
#define LD4(base, off)  (*(const fvec4*)((base) + (off)))
#define LDNT(base, off) __builtin_nontemporal_load((const fvec4*)((base) + (off)))

// min-waves=2: permits up to 256 VGPR so the 3-slot pipeline can live in
// registers. r4 evidence: min-waves=6 -> 40 VGPR + 285 MB scratch. r5
// evidence: default heuristic clamps to 60 VGPR + AGPR shuffles.
__global__ __launch_bounds__(TPB, 2) void loss_main(const float* __restrict__ outs,
                                                    const float* __restrict__ tgts,
                                                    double* __restrict__ partial) {
    const int lane = threadIdx.x & 63;
    const int wv   = threadIdx.x >> 6;

    // XCD-aware bijective swizzle: 2048 = 8 XCDs x 256. Adjacent logical blocks
    // (x-chunks sharing a boundary column) land on the same XCD's L2.
    const int bid = (int)blockIdx.x;
    const int blk = (bid & 7) * (BLOCKS / 8) + (bid >> 3);

    // blk = ((b*16 + sy)*64 + xc) : xc fastest
    const int b  = blk >> 10;
    const int r  = blk & 1023;
    const int sy = r >> 6;
    const int xc = r & 63;
    const int x0 = xc * XS;

    const int row_l = wv * 4 + (lane >> 4);   // 0..15 (block-local y row)
    const int zi    = (lane & 15) << 2;       // 0,4,...,60
    const int y     = sy * RPB + row_l;
    const int yp    = (y < Y - 1) ? (y + 1) : y;   // clamped (cells masked at y=255)
    const bool yvalid = (y < Y - 1);

    const float* ob = outs + (size_t)b * 3 * CO;
    const float* tb = tgts + (size_t)b * 4 * CO;

    const uint32_t yZzi  = (uint32_t)y  * Z + zi;
    const uint32_t ypZzi = (uint32_t)yp * Z + zi;
    constexpr uint32_t C1 = (uint32_t)CO, C2 = 2u * CO, C3 = 3u * CO;

    // 3-slot stencil rotation (col i-1, i, i+1-in-flight), 2-slot targets
    fvec4 sbx0[3], sby0[3], sbz0[3], szc0[3];   // row y
    fvec4 sbx1[3], sby1[3], sbz1[3], szc1[3];   // row y+1
    fvec4 tg0[2], tg1[2], tg2[2];

    // issue stencil loads for column x0+c into slot s (8 x dwordx4)
    auto issue_stn = [&](int c, int s) {
        const uint32_t xb = (uint32_t)((x0 + c < X) ? (x0 + c) : (X - 1)) * YZ;
        const uint32_t o0 = xb + yZzi, o1 = xb + ypZzi;
        sbx0[s] = LD4(ob, o0);        sbx1[s] = LD4(ob, o1);
        sby0[s] = LD4(ob, C1 + o0);   sby1[s] = LD4(ob, C1 + o1);
        sbz0[s] = LD4(ob, C2 + o0);   sbz1[s] = LD4(ob, C2 + o1);
        szc0[s] = LD4(tb, C3 + o0);   szc1[s] = LD4(tb, C3 + o1);
    };
    // issue pointwise-target loads for column x0+c into slot s (3 x dwordx4, NT)
    auto issue_tgt = [&](int c, int s) {
        const uint32_t o0 = (uint32_t)(x0 + c) * YZ + yZzi;
        tg0[s] = LDNT(tb, o0);
        tg1[s] = LDNT(tb, C1 + o0);
        tg2[s] = LDNT(tb, C2 + o0);
    };

    // prologue: column x0 into slot 0 / tslot 0
    issue_stn(0, 0);
    issue_tgt(0, 0);

    double s_pt = 0.0, s_dv = 0.0;

    #pragma unroll
    for (int i = 0; i <= XS; ++i) {
        const int cs = i % 3;            // col i        (compile-time after unroll)
        const int ps = (i + 2) % 3;      // col i-1
        const int ts = i & 1;            // col i targets

        // ---- 1. issue next column's loads FIRST: in flight across this
        //         iteration's compute (the pipeline) ----
        if (i < XS)      issue_stn(i + 1, (i + 1) % 3);
        if (i < XS - 1)  issue_tgt(i + 1, (i + 1) & 1);

        // ---- 2. pointwise losses at column x0+i (loaded >=1 iteration ago) ----
        if (i < XS) {
            float pt4 = 0.0f;
            #pragma unroll
            for (int c = 0; c < 4; ++c) {
                const float bxp = F4C(sbx0[cs], c), byp = F4C(sby0[cs], c), bzp = F4C(sbz0[cs], c);
                const float bxt = F4C(tg0[ts], c), byt = F4C(tg1[ts], c), bzt = F4C(tg2[ts], c);
                const float bxt2 = bxt * bxt, byt2 = byt * byt, bzt2 = bzt * bzt;
                const float dxy = bxt2 + byt2;
                const float tq = bxp * bxp + byp * byp - dxy;
                const float e1 = tq * tq * RCPF(dxy + EPSc);
                const float dd = bzp - bzt;
                const float dd2 = dd * dd;
                const float e2 = dd2 * dd2 * RCPF(bzt2 + EPSc);
                const float cr = bxp * byt - byp * bxt;
                const float e3 = cr * cr * RCPF(dxy + bzt2 + EPSc);
                pt4 += e1 + e2 + e3;
            }
            s_pt += (double)pt4;
        }

        // ---- 3. divergence cells between cols x0+i-1 (ps) and x0+i (cs) ----
        if (i >= 1 && (x0 + i - 1) < X - 1) {          // block-uniform
            float sxp[5], sxm[5], syp[5], sym[5];
            float zxp[5], zxm[5], zyp[5], zym[5];
            float Sx[5], Sy[5], Sz[5], G2[5];

            #pragma unroll
            for (int t = 0; t < 4; ++t) {
                const float bx00 = F4C(sbx0[ps], t), bx10 = F4C(sbx0[cs], t);
                const float bx01 = F4C(sbx1[ps], t), bx11 = F4C(sbx1[cs], t);
                const float by00 = F4C(sby0[ps], t), by10 = F4C(sby0[cs], t);
                const float by01 = F4C(sby1[ps], t), by11 = F4C(sby1[cs], t);
                const float bz00 = F4C(sbz0[ps], t), bz10 = F4C(sbz0[cs], t);
                const float bz01 = F4C(sbz1[ps], t), bz11 = F4C(sbz1[cs], t);
                const float zc00 = F4C(szc0[ps], t), zc10 = F4C(szc0[cs], t);
                const float zc01 = F4C(szc1[ps], t), zc11 = F4C(szc1[cs], t);

                sxp[t] = bx10 + bx11;   sxm[t] = bx00 + bx01;
                syp[t] = by01 + by11;   sym[t] = by00 + by10;
                zxp[t] = zc10 + zc11;   zxm[t] = zc00 + zc01;
                zyp[t] = zc01 + zc11;   zym[t] = zc00 + zc10;
                Sx[t] = sxp[t] + sxm[t];
                Sy[t] = syp[t] + sym[t];
                Sz[t] = (bz00 + bz01) + (bz10 + bz11);
                G2[t] = 0.025f * Sz[t]
                      + SIXTH * ((bx00 + sxp[t]) * (zc00 - zc10)
                               + (bx01 + sxp[t]) * (zc01 - zc11)
                               + (by10 + syp[t]) * (zc10 - zc11)
                               + (by00 + syp[t]) * (zc00 - zc01));
            }
            // level 4 = lane+1's level 0 (z is the lane-contiguous dim)
            sxp[4] = __shfl_down(sxp[0], 1);
            sxm[4] = __shfl_down(sxm[0], 1);
            syp[4] = __shfl_down(syp[0], 1);
            sym[4] = __shfl_down(sym[0], 1);
            zxp[4] = __shfl_down(zxp[0], 1);
            zxm[4] = __shfl_down(zxm[0], 1);
            zyp[4] = __shfl_down(zyp[0], 1);
            zym[4] = __shfl_down(zym[0], 1);
            Sz[4]  = __shfl_down(Sz[0],  1);
            G2[4]  = __shfl_down(G2[0],  1);
            Sx[4] = sxp[4] + sxm[4];
            Sy[4] = syp[4] + sym[4];

            float dv4 = 0.0f;
            #pragma unroll
            for (int c = 0; c < 4; ++c) {
                const float fx = (sxp[c] + sxp[c+1]) * (zxp[c+1] - zxp[c])
                               - (sxm[c] + sxm[c+1]) * (zxm[c+1] - zxm[c])
                               + (syp[c] + syp[c+1]) * (zyp[c+1] - zyp[c])
                               - (sym[c] + sym[c+1]) * (zym[c+1] - zym[c]);
                const float num2 = 0.125f * fx + (G2[c+1] - G2[c]);
                const float SxS = Sx[c] + Sx[c+1];
                const float SyS = Sy[c] + Sy[c+1];
                const float SzS = Sz[c] + Sz[c+1];
                const float q = SxS * SxS + SyS * SyS + SzS * SzS;
                const float den = 0.015625f * q + EPSc;
                const float v = num2 * num2 * RCPF(den);
                const bool ok = yvalid && ((zi + c) < Z - 1);
                dv4 += ok ? v : 0.0f;
            }
            s_dv += (double)dv4;
        }
    }

    // wave reduction (64 lanes)
    for (int off = 32; off > 0; off >>= 1) {
        s_pt += __shfl_down(s_pt, off);
        s_dv += __shfl_down(s_dv, off);
    }

    __shared__ double lds_pt[WPB];
    __shared__ double lds_dv[WPB];
    if (lane == 0) { lds_pt[wv] = s_pt; lds_dv[wv] = s_dv; }
    __syncthreads();
    if (threadIdx.x == 0) {
        double p = 0.0, d = 0.0;
        #pragma unroll
        for (int w = 0; w < WPB; ++w) { p += lds_pt[w]; d += lds_dv[w]; }
        // write by LOGICAL block id -> partial[] contents identical to unswizzled
        partial[2 * blk]     = p;
        partial[2 * blk + 1] = d;
    }
}

__global__ __launch_bounds__(256) void loss_finalize(const double* __restrict__ partial,
                                                     float* __restrict__ out) {
    double s0 = 0.0, s1 = 0.0;
    for (int i = threadIdx.x; i < BLOCKS; i += 256) {
        s0 += partial[2 * i];
        s1 += partial[2 * i + 1];
    }
    const int lane = threadIdx.x & 63;
    const int wave = threadIdx.x >> 6;
    for (int off = 32; off > 0; off >>= 1) {
        s0 += __shfl_down(s0, off);
        s1 += __shfl_down(s1, off);
    }
    __shared__ double l0[4], l1[4];
    if (lane == 0) { l0[wave] = s0; l1[wave] = s1; }
    __syncthreads();
    if (threadIdx.x == 0) {
        double p = 0.0, d = 0.0;
        #pragma unroll
        for (int w = 0; w < 4; ++w) { p += l0[w]; d += l1[w]; }
        // out0 = W_B*loss_b + W_PARALLEL*loss_parallel = 1000 * sum_pt / N
        const double out0 = 1000.0 * (p / (double)N_PTS);
        // s_dv accumulates v = num2^2/den with num = 0.1*num2:
        //   out1 = 100 * (0.01 * sum_v / M) / 1e-4 = 1e4 * sum_v / M
        const double out1 = 10000.0 * (d / (double)M_CELLS);
        out[0] = (float)out0;
        out[1] = (float)out1;
    }
}

extern "C" void kernel_launch(void* const* d_in, const int* in_sizes, int n_in,
                              void* d_out, int out_size, void* d_ws, size_t ws_size,
                              hipStream_t stream) {
    const float* outs = (const float*)d_in[0];   // (2,3,256,256,64) f32
    const float* tgts = (const float*)d_in[1];   // (2,4,256,256,64) f32
    float* out = (float*)d_out;                  // 2 scalars f32
    double* partial = (double*)d_ws;             // BLOCKS*2 doubles = 32 KB

    loss_main<<<BLOCKS, TPB, 0, stream>>>(outs, tgts, partial);
    loss_finalize<<<1, 256, 0, stream>>>(partial, out);
}